// Round 1
// baseline (367.133 us; speedup 1.0000x reference)
//
#include <hip/hip_runtime.h>
#include <math.h>

#define NSENT 65536
#define NBAGS 4096
#define DIM 768
#define D4 192            // DIM/4
#define FLATC 53
#define KTOT 2304         // 3*DIM
#define K4 576            // KTOT/4
#define CHUNK 1024
#define BB 8              // bags per block in probs kernel

__device__ __forceinline__ float wsum(float v) {
#pragma unroll
  for (int o = 32; o; o >>= 1) v += __shfl_xor(v, o);
  return v;
}
__device__ __forceinline__ float wmax(float v) {
#pragma unroll
  for (int o = 32; o; o >>= 1) v = fmaxf(v, __shfl_xor(v, o));
  return v;
}

// One block per bag. 192 threads = 3 waves (one wave per attention layer for
// the softmax reductions; wave-per-sentence for logits; all threads for the
// float4 column-sliced weighted accumulation).
__global__ __launch_bounds__(192) void bag_kernel(
    const float* __restrict__ x, const int* __restrict__ q,
    const int* __restrict__ scope, const float* __restrict__ aw,
    float* __restrict__ out) {
  const int b = blockIdx.x;
  const int s0 = scope[b];
  const int s1 = scope[b + 1];
  const int len = s1 - s0;
  const int tid = threadIdx.x;   // 0..191
  const int wave = tid >> 6;     // 0..2
  const int lane = tid & 63;

  __shared__ float lg[CHUNK][3];
  __shared__ float sm[3], se[3];

  float m[3] = {-INFINITY, -INFINITY, -INFINITY};
  float dsum[3] = {0.f, 0.f, 0.f};
  float4 acc[3];
#pragma unroll
  for (int l = 0; l < 3; l++) acc[l] = make_float4(0.f, 0.f, 0.f, 0.f);

  const float4* __restrict__ X4 = (const float4*)x;
  const float4* __restrict__ AW4 = (const float4*)aw;

  for (int cs = 0; cs < len; cs += CHUNK) {
    const int clen = min(CHUNK, len - cs);

    // ---- Phase A: logits for this chunk (wave per sentence) ----
    for (int i = wave; i < clen; i += 3) {
      const int n = s0 + cs + i;
      const int q0 = q[3 * n + 0];
      const int q1 = q[3 * n + 1];
      const int q2 = q[3 * n + 2];
      const float4* xr = X4 + (size_t)n * D4;
      const float4* a0 = AW4 + (size_t)q0 * D4;
      const float4* a1 = AW4 + (size_t)q1 * D4;
      const float4* a2 = AW4 + (size_t)q2 * D4;
      float p0 = 0.f, p1 = 0.f, p2 = 0.f;
#pragma unroll
      for (int j = 0; j < 3; j++) {
        const int idx = lane + 64 * j;
        float4 xv = xr[idx];
        float4 v0 = a0[idx];
        float4 v1 = a1[idx];
        float4 v2 = a2[idx];
        p0 += xv.x * v0.x + xv.y * v0.y + xv.z * v0.z + xv.w * v0.w;
        p1 += xv.x * v1.x + xv.y * v1.y + xv.z * v1.z + xv.w * v1.w;
        p2 += xv.x * v2.x + xv.y * v2.y + xv.z * v2.z + xv.w * v2.w;
      }
      p0 = wsum(p0);
      p1 = wsum(p1);
      p2 = wsum(p2);
      if (lane == 0) {
        lg[i][0] = p0;
        lg[i][1] = p1;
        lg[i][2] = p2;
      }
    }
    __syncthreads();

    // ---- per-layer chunk max / exp / sum (wave w handles layer w) ----
    {
      const int l = wave;  // exactly 3 waves
      float cm = -INFINITY;
      for (int i = lane; i < clen; i += 64) cm = fmaxf(cm, lg[i][l]);
      cm = wmax(cm);
      const float mn = fmaxf(m[l], cm);
      float es = 0.f;
      for (int i = lane; i < clen; i += 64) {
        const float e = __expf(lg[i][l] - mn);
        es += e;
        lg[i][l] = e;  // store UNNORMALIZED weight
      }
      es = wsum(es);
      if (lane == 0) {
        sm[l] = mn;
        se[l] = es;
      }
    }
    __syncthreads();

    // ---- rescale running state (replicated per-thread) ----
#pragma unroll
    for (int l = 0; l < 3; l++) {
      const float mn = sm[l];
      const float sc = __expf(m[l] - mn);  // exp(-inf)=0 on first chunk
      m[l] = mn;
      dsum[l] = dsum[l] * sc + se[l];
      acc[l].x *= sc; acc[l].y *= sc; acc[l].z *= sc; acc[l].w *= sc;
    }

    // ---- Phase B: weighted accumulation, float4 column slice per thread ----
    for (int i = 0; i < clen; i++) {
      const float w0 = lg[i][0];  // LDS broadcast
      const float w1 = lg[i][1];
      const float w2 = lg[i][2];
      const float4 xv = X4[(size_t)(s0 + cs + i) * D4 + tid];
      acc[0].x += w0 * xv.x; acc[0].y += w0 * xv.y; acc[0].z += w0 * xv.z; acc[0].w += w0 * xv.w;
      acc[1].x += w1 * xv.x; acc[1].y += w1 * xv.y; acc[1].z += w1 * xv.z; acc[1].w += w1 * xv.w;
      acc[2].x += w2 * xv.x; acc[2].y += w2 * xv.y; acc[2].z += w2 * xv.z; acc[2].w += w2 * xv.w;
    }
    __syncthreads();  // protect lg before next chunk
  }

  // ---- finalize: normalize by softmax denom, write both layouts ----
  float4* o0 = (float4*)out;                              // stack [3][B][D]
  float4* o1 = (float4*)(out + (size_t)3 * NBAGS * DIM);  // lt [B][3*D]
#pragma unroll
  for (int l = 0; l < 3; l++) {
    const float inv = (dsum[l] > 0.f) ? (1.f / dsum[l]) : 0.f;
    float4 v = acc[l];
    v.x *= inv; v.y *= inv; v.z *= inv; v.w *= inv;
    o0[((size_t)l * NBAGS + b) * D4 + tid] = v;
    o1[(size_t)b * K4 + l * D4 + tid] = v;
  }
}

// probs = logits_total @ relation_weight^T + bias
// k-outer / bag-inner so relation_weight (488KB) is read once per block.
__global__ __launch_bounds__(256) void probs_kernel(
    const float* __restrict__ lt, const float* __restrict__ rw,
    const float* __restrict__ bias, float* __restrict__ out) {
  const int bag0 = blockIdx.x * BB;
  const int c = threadIdx.x >> 2;  // 0..63
  const int p = threadIdx.x & 3;   // 0..3 (K split in 4 chunks of 576)
  float acc[BB];
#pragma unroll
  for (int b = 0; b < BB; b++) acc[b] = 0.f;

  if (c < FLATC) {
    const float4* rwr = (const float4*)(rw + (size_t)c * KTOT + p * 576);
    const float4* l0 = (const float4*)(lt + (size_t)bag0 * KTOT + p * 576);
    for (int kk = 0; kk < 144; kk++) {  // 576/4
      const float4 w4 = rwr[kk];
#pragma unroll
      for (int b = 0; b < BB; b++) {
        const float4 l4 = l0[(size_t)b * K4 + kk];
        acc[b] += l4.x * w4.x + l4.y * w4.y + l4.z * w4.z + l4.w * w4.w;
      }
    }
  }

  __shared__ float sred[BB][64][4];
#pragma unroll
  for (int b = 0; b < BB; b++) sred[b][c][p] = acc[b];
  __syncthreads();

  for (int idx = threadIdx.x; idx < BB * FLATC; idx += 256) {
    const int b = idx / FLATC;
    const int cc = idx % FLATC;
    out[(size_t)(bag0 + b) * FLATC + cc] =
        sred[b][cc][0] + sred[b][cc][1] + sred[b][cc][2] + sred[b][cc][3] +
        bias[cc];
  }
}

extern "C" void kernel_launch(void* const* d_in, const int* in_sizes, int n_in,
                              void* d_out, int out_size, void* d_ws,
                              size_t ws_size, hipStream_t stream) {
  const float* x = (const float*)d_in[0];
  const int* aq = (const int*)d_in[1];
  const int* scope = (const int*)d_in[2];
  const float* aw = (const float*)d_in[3];
  const float* rw = (const float*)d_in[4];
  const float* bias = (const float*)d_in[5];
  float* out = (float*)d_out;

  hipLaunchKernelGGL(bag_kernel, dim3(NBAGS), dim3(192), 0, stream, x, aq,
                     scope, aw, out);

  const float* lt = out + (size_t)3 * NBAGS * DIM;
  float* probs = out + (size_t)3 * NBAGS * DIM + (size_t)NBAGS * KTOT;
  hipLaunchKernelGGL(probs_kernel, dim3(NBAGS / BB), dim3(256), 0, stream, lt,
                     rw, bias, probs);
}

// Round 2
// 211.221 us; speedup vs baseline: 1.7381x; 1.7381x over previous
//
#include <hip/hip_runtime.h>
#include <math.h>

#define NSENT 65536
#define NBAGS 4096
#define DIM 768
#define D4 192            // DIM/4
#define FLATC 53
#define KTOT 2304         // 3*DIM
#define K4 576            // KTOT/4 (float4 per lt row)
#define CHUNK 1024
#define KC 576            // K elements per staged chunk
#define KC4 144           // float4 per chunk row
#define NBB 16            // bags per block in probs kernel
#define PTHR 256

__device__ __forceinline__ float wsum(float v) {
#pragma unroll
  for (int o = 32; o; o >>= 1) v += __shfl_xor(v, o);
  return v;
}
__device__ __forceinline__ float wmax(float v) {
#pragma unroll
  for (int o = 32; o; o >>= 1) v = fmaxf(v, __shfl_xor(v, o));
  return v;
}

// One block per bag. 192 threads = 3 waves.
__global__ __launch_bounds__(192) void bag_kernel(
    const float* __restrict__ x, const int* __restrict__ q,
    const int* __restrict__ scope, const float* __restrict__ aw,
    float* __restrict__ out) {
  const int b = blockIdx.x;
  const int s0 = scope[b];
  const int s1 = scope[b + 1];
  const int len = s1 - s0;
  const int tid = threadIdx.x;   // 0..191
  const int wave = tid >> 6;     // 0..2
  const int lane = tid & 63;

  __shared__ float lg[CHUNK][3];
  __shared__ float sm[3], se[3];

  float m[3] = {-INFINITY, -INFINITY, -INFINITY};
  float dsum[3] = {0.f, 0.f, 0.f};
  float4 acc[3];
#pragma unroll
  for (int l = 0; l < 3; l++) acc[l] = make_float4(0.f, 0.f, 0.f, 0.f);

  const float4* __restrict__ X4 = (const float4*)x;
  const float4* __restrict__ AW4 = (const float4*)aw;

  for (int cs = 0; cs < len; cs += CHUNK) {
    const int clen = min(CHUNK, len - cs);

    // ---- Phase A: logits for this chunk (wave per sentence) ----
    for (int i = wave; i < clen; i += 3) {
      const int n = s0 + cs + i;
      const int q0 = q[3 * n + 0];
      const int q1 = q[3 * n + 1];
      const int q2 = q[3 * n + 2];
      const float4* xr = X4 + (size_t)n * D4;
      const float4* a0 = AW4 + (size_t)q0 * D4;
      const float4* a1 = AW4 + (size_t)q1 * D4;
      const float4* a2 = AW4 + (size_t)q2 * D4;
      float p0 = 0.f, p1 = 0.f, p2 = 0.f;
#pragma unroll
      for (int j = 0; j < 3; j++) {
        const int idx = lane + 64 * j;
        float4 xv = xr[idx];
        float4 v0 = a0[idx];
        float4 v1 = a1[idx];
        float4 v2 = a2[idx];
        p0 += xv.x * v0.x + xv.y * v0.y + xv.z * v0.z + xv.w * v0.w;
        p1 += xv.x * v1.x + xv.y * v1.y + xv.z * v1.z + xv.w * v1.w;
        p2 += xv.x * v2.x + xv.y * v2.y + xv.z * v2.z + xv.w * v2.w;
      }
      p0 = wsum(p0);
      p1 = wsum(p1);
      p2 = wsum(p2);
      if (lane == 0) {
        lg[i][0] = p0;
        lg[i][1] = p1;
        lg[i][2] = p2;
      }
    }
    __syncthreads();

    // ---- per-layer chunk max / exp / sum (wave w handles layer w) ----
    {
      const int l = wave;
      float cm = -INFINITY;
      for (int i = lane; i < clen; i += 64) cm = fmaxf(cm, lg[i][l]);
      cm = wmax(cm);
      const float mn = fmaxf(m[l], cm);
      float es = 0.f;
      for (int i = lane; i < clen; i += 64) {
        const float e = __expf(lg[i][l] - mn);
        es += e;
        lg[i][l] = e;  // store UNNORMALIZED weight
      }
      es = wsum(es);
      if (lane == 0) {
        sm[l] = mn;
        se[l] = es;
      }
    }
    __syncthreads();

    // ---- rescale running state ----
#pragma unroll
    for (int l = 0; l < 3; l++) {
      const float mn = sm[l];
      const float sc = __expf(m[l] - mn);  // exp(-inf)=0 on first chunk
      m[l] = mn;
      dsum[l] = dsum[l] * sc + se[l];
      acc[l].x *= sc; acc[l].y *= sc; acc[l].z *= sc; acc[l].w *= sc;
    }

    // ---- Phase B: weighted accumulation, float4 column slice per thread ----
    for (int i = 0; i < clen; i++) {
      const float w0 = lg[i][0];
      const float w1 = lg[i][1];
      const float w2 = lg[i][2];
      const float4 xv = X4[(size_t)(s0 + cs + i) * D4 + tid];
      acc[0].x += w0 * xv.x; acc[0].y += w0 * xv.y; acc[0].z += w0 * xv.z; acc[0].w += w0 * xv.w;
      acc[1].x += w1 * xv.x; acc[1].y += w1 * xv.y; acc[1].z += w1 * xv.z; acc[1].w += w1 * xv.w;
      acc[2].x += w2 * xv.x; acc[2].y += w2 * xv.y; acc[2].z += w2 * xv.z; acc[2].w += w2 * xv.w;
    }
    __syncthreads();
  }

  // ---- finalize ----
  float4* o0 = (float4*)out;                              // stack [3][B][D]
  float4* o1 = (float4*)(out + (size_t)3 * NBAGS * DIM);  // lt [B][3*D]
#pragma unroll
  for (int l = 0; l < 3; l++) {
    const float inv = (dsum[l] > 0.f) ? (1.f / dsum[l]) : 0.f;
    float4 v = acc[l];
    v.x *= inv; v.y *= inv; v.z *= inv; v.w *= inv;
    o0[((size_t)l * NBAGS + b) * D4 + tid] = v;
    o1[(size_t)b * K4 + l * D4 + tid] = v;
  }
}

// probs = logits_total @ relation_weight^T + bias.
// rw staged in LDS once per K-chunk per block; lt slice in registers
// (each thread owns one bag x one 1/16 K-slice -> lt read exactly once).
__global__ __launch_bounds__(PTHR) void probs_kernel(
    const float* __restrict__ lt, const float* __restrict__ rw,
    const float* __restrict__ bias, float* __restrict__ out) {
  __shared__ float srw[FLATC * KC];  // 122,112 B
  const int tid = threadIdx.x;
  const int bag = tid >> 4;          // 0..15
  const int ksub = tid & 15;         // 0..15
  const int bag0 = blockIdx.x * NBB;

  float acc[FLATC];
#pragma unroll
  for (int c = 0; c < FLATC; c++) acc[c] = 0.f;

  const float4* __restrict__ RW4 = (const float4*)rw;
  const float4* __restrict__ LT4 = (const float4*)lt;
  float4* SRW4 = (float4*)srw;

  for (int chunk = 0; chunk < 4; chunk++) {
    __syncthreads();  // protect srw from previous chunk's readers
    for (int idx = tid; idx < FLATC * KC4; idx += PTHR) {
      const int c = idx / KC4;
      const int kk = idx - c * KC4;
      SRW4[idx] = RW4[(size_t)c * K4 + chunk * KC4 + kk];
    }
    __syncthreads();

    float4 lreg[9];
    const float4* lp = LT4 + (size_t)(bag0 + bag) * K4 + chunk * KC4 + ksub * 9;
#pragma unroll
    for (int j = 0; j < 9; j++) lreg[j] = lp[j];

#pragma unroll
    for (int c = 0; c < FLATC; c++) {
      const float4* wp = SRW4 + c * KC4 + ksub * 9;
      float s = 0.f;
#pragma unroll
      for (int j = 0; j < 9; j++) {
        const float4 w4 = wp[j];
        s += lreg[j].x * w4.x + lreg[j].y * w4.y + lreg[j].z * w4.z +
             lreg[j].w * w4.w;
      }
      acc[c] += s;
    }
  }

  // reduce acc over the 16 ksub threads per bag, via LDS (reuse srw)
  __syncthreads();
  float* sred = srw;  // [NBB][FLATC][16] = 13568 floats, fits
#pragma unroll
  for (int c = 0; c < FLATC; c++)
    sred[(bag * FLATC + c) * 16 + ksub] = acc[c];
  __syncthreads();
  for (int idx = tid; idx < NBB * FLATC; idx += PTHR) {
    const int b = idx / FLATC;
    const int c = idx - b * FLATC;
    const float* p = sred + idx * 16;
    float s = 0.f;
#pragma unroll
    for (int j = 0; j < 16; j++) s += p[j];
    out[(size_t)(bag0 + b) * FLATC + c] = s + bias[c];
  }
}

extern "C" void kernel_launch(void* const* d_in, const int* in_sizes, int n_in,
                              void* d_out, int out_size, void* d_ws,
                              size_t ws_size, hipStream_t stream) {
  const float* x = (const float*)d_in[0];
  const int* aq = (const int*)d_in[1];
  const int* scope = (const int*)d_in[2];
  const float* aw = (const float*)d_in[3];
  const float* rw = (const float*)d_in[4];
  const float* bias = (const float*)d_in[5];
  float* out = (float*)d_out;

  hipLaunchKernelGGL(bag_kernel, dim3(NBAGS), dim3(192), 0, stream, x, aq,
                     scope, aw, out);

  const float* lt = out + (size_t)3 * NBAGS * DIM;
  float* probs = out + (size_t)3 * NBAGS * DIM + (size_t)NBAGS * KTOT;
  hipLaunchKernelGGL(probs_kernel, dim3(NBAGS / NBB), dim3(PTHR), 0, stream,
                     lt, rw, bias, probs);
}

// Round 3
// 187.334 us; speedup vs baseline: 1.9598x; 1.1275x over previous
//
#include <hip/hip_runtime.h>
#include <math.h>

#define NSENT 65536
#define NBAGS 4096
#define DIM 768
#define D4 192            // DIM/4
#define FLATC 53
#define CPAD 64           // padded class count for MFMA
#define KTOT 2304         // 3*DIM
#define K4 576            // KTOT/4
#define CHUNK 256

typedef short bf16x8 __attribute__((ext_vector_type(8)));
typedef float f32x4 __attribute__((ext_vector_type(4)));

__device__ __forceinline__ float wsum(float v) {
#pragma unroll
  for (int o = 32; o; o >>= 1) v += __shfl_xor(v, o);
  return v;
}
__device__ __forceinline__ float wmax(float v) {
#pragma unroll
  for (int o = 32; o; o >>= 1) v = fmaxf(v, __shfl_xor(v, o));
  return v;
}
__device__ __forceinline__ float dot4(float4 a, float4 b) {
  return a.x * b.x + a.y * b.y + a.z * b.z + a.w * b.w;
}
// f32 -> bf16 round-to-nearest-even
__device__ __forceinline__ unsigned short f2bf(float f) {
  unsigned int u = __float_as_uint(f);
  return (unsigned short)((u + 0x7FFFu + ((u >> 16) & 1u)) >> 16);
}

// One block per bag. 192 threads = 3 waves.
__global__ __launch_bounds__(192) void bag_kernel(
    const float* __restrict__ x, const int* __restrict__ q,
    const int* __restrict__ scope, const float* __restrict__ aw,
    float* __restrict__ out, unsigned short* __restrict__ lt16) {
  const int b = blockIdx.x;
  const int s0 = scope[b];
  const int s1 = scope[b + 1];
  const int len = s1 - s0;
  const int tid = threadIdx.x;   // 0..191
  const int wave = tid >> 6;     // 0..2
  const int lane = tid & 63;

  __shared__ float lg[CHUNK][3];
  __shared__ int sq[CHUNK][3];
  __shared__ float sm[3], se[3];

  float m[3] = {-INFINITY, -INFINITY, -INFINITY};
  float dsum[3] = {0.f, 0.f, 0.f};
  float4 acc[3];
#pragma unroll
  for (int l = 0; l < 3; l++) acc[l] = make_float4(0.f, 0.f, 0.f, 0.f);

  const float4* __restrict__ X4 = (const float4*)x;
  const float4* __restrict__ AW4 = (const float4*)aw;

  for (int cs = 0; cs < len; cs += CHUNK) {
    const int clen = min(CHUNK, len - cs);

    // ---- Phase A0: stage q for the whole chunk (coalesced, breaks the
    //      per-sentence q->aw dependent chain) ----
    for (int idx = tid; idx < 3 * clen; idx += 192)
      ((int*)sq)[idx] = q[(size_t)(s0 + cs) * 3 + idx];
    __syncthreads();

    // ---- Phase A: wave per sentence, 2 sentences in flight ----
    for (int i0 = wave; i0 < clen; i0 += 6) {
      const int i1 = i0 + 3;
      const bool h2 = (i1 < clen);
      const int i1c = h2 ? i1 : i0;
      const int n0 = s0 + cs + i0;
      const int n1 = s0 + cs + i1c;
      const int qa0 = sq[i0][0], qa1 = sq[i0][1], qa2 = sq[i0][2];
      const int qb0 = sq[i1c][0], qb1 = sq[i1c][1], qb2 = sq[i1c][2];
      const float4* xr0 = X4 + (size_t)n0 * D4;
      const float4* xr1 = X4 + (size_t)n1 * D4;
      const float4* A00 = AW4 + (size_t)qa0 * D4;
      const float4* A01 = AW4 + (size_t)qa1 * D4;
      const float4* A02 = AW4 + (size_t)qa2 * D4;
      const float4* A10 = AW4 + (size_t)qb0 * D4;
      const float4* A11 = AW4 + (size_t)qb1 * D4;
      const float4* A12 = AW4 + (size_t)qb2 * D4;
      float p00 = 0.f, p01 = 0.f, p02 = 0.f;
      float p10 = 0.f, p11 = 0.f, p12 = 0.f;
#pragma unroll
      for (int j = 0; j < 3; j++) {
        const int idx = lane + 64 * j;
        const float4 x0 = xr0[idx];
        const float4 x1 = xr1[idx];
        p00 += dot4(x0, A00[idx]);
        p01 += dot4(x0, A01[idx]);
        p02 += dot4(x0, A02[idx]);
        p10 += dot4(x1, A10[idx]);
        p11 += dot4(x1, A11[idx]);
        p12 += dot4(x1, A12[idx]);
      }
      p00 = wsum(p00); p01 = wsum(p01); p02 = wsum(p02);
      p10 = wsum(p10); p11 = wsum(p11); p12 = wsum(p12);
      if (lane == 0) {
        lg[i0][0] = p00; lg[i0][1] = p01; lg[i0][2] = p02;
        if (h2) { lg[i1][0] = p10; lg[i1][1] = p11; lg[i1][2] = p12; }
      }
    }
    __syncthreads();

    // ---- per-layer chunk max / exp / sum (wave w handles layer w) ----
    {
      const int l = wave;
      float cm = -INFINITY;
      for (int i = lane; i < clen; i += 64) cm = fmaxf(cm, lg[i][l]);
      cm = wmax(cm);
      const float mn = fmaxf(m[l], cm);
      float es = 0.f;
      for (int i = lane; i < clen; i += 64) {
        const float e = __expf(lg[i][l] - mn);
        es += e;
        lg[i][l] = e;  // store UNNORMALIZED weight
      }
      es = wsum(es);
      if (lane == 0) {
        sm[l] = mn;
        se[l] = es;
      }
    }
    __syncthreads();

    // ---- rescale running state ----
#pragma unroll
    for (int l = 0; l < 3; l++) {
      const float mn = sm[l];
      const float sc = __expf(m[l] - mn);  // exp(-inf)=0 on first chunk
      m[l] = mn;
      dsum[l] = dsum[l] * sc + se[l];
      acc[l].x *= sc; acc[l].y *= sc; acc[l].z *= sc; acc[l].w *= sc;
    }

    // ---- Phase B: weighted accumulation, 2-sentence unroll ----
    {
      int i = 0;
      for (; i + 1 < clen; i += 2) {
        const float w00 = lg[i][0], w01 = lg[i][1], w02 = lg[i][2];
        const float w10 = lg[i + 1][0], w11 = lg[i + 1][1], w12 = lg[i + 1][2];
        const float4 x0 = X4[(size_t)(s0 + cs + i) * D4 + tid];
        const float4 x1 = X4[(size_t)(s0 + cs + i + 1) * D4 + tid];
        acc[0].x += w00 * x0.x + w10 * x1.x;
        acc[0].y += w00 * x0.y + w10 * x1.y;
        acc[0].z += w00 * x0.z + w10 * x1.z;
        acc[0].w += w00 * x0.w + w10 * x1.w;
        acc[1].x += w01 * x0.x + w11 * x1.x;
        acc[1].y += w01 * x0.y + w11 * x1.y;
        acc[1].z += w01 * x0.z + w11 * x1.z;
        acc[1].w += w01 * x0.w + w11 * x1.w;
        acc[2].x += w02 * x0.x + w12 * x1.x;
        acc[2].y += w02 * x0.y + w12 * x1.y;
        acc[2].z += w02 * x0.z + w12 * x1.z;
        acc[2].w += w02 * x0.w + w12 * x1.w;
      }
      if (i < clen) {
        const float w0 = lg[i][0], w1 = lg[i][1], w2 = lg[i][2];
        const float4 xv = X4[(size_t)(s0 + cs + i) * D4 + tid];
        acc[0].x += w0 * xv.x; acc[0].y += w0 * xv.y; acc[0].z += w0 * xv.z; acc[0].w += w0 * xv.w;
        acc[1].x += w1 * xv.x; acc[1].y += w1 * xv.y; acc[1].z += w1 * xv.z; acc[1].w += w1 * xv.w;
        acc[2].x += w2 * xv.x; acc[2].y += w2 * xv.y; acc[2].z += w2 * xv.z; acc[2].w += w2 * xv.w;
      }
    }
    __syncthreads();
  }

  // ---- finalize: normalize, write both f32 layouts + bf16 copy for GEMM ----
  float4* o0 = (float4*)out;                              // stack [3][B][D]
  float4* o1 = (float4*)(out + (size_t)3 * NBAGS * DIM);  // lt [B][3*D]
  ushort4* l16 = (ushort4*)(lt16 + (size_t)b * KTOT);
#pragma unroll
  for (int l = 0; l < 3; l++) {
    const float inv = (dsum[l] > 0.f) ? (1.f / dsum[l]) : 0.f;
    float4 v = acc[l];
    v.x *= inv; v.y *= inv; v.z *= inv; v.w *= inv;
    o0[((size_t)l * NBAGS + b) * D4 + tid] = v;
    o1[(size_t)b * K4 + l * D4 + tid] = v;
    ushort4 h;
    h.x = f2bf(v.x); h.y = f2bf(v.y); h.z = f2bf(v.z); h.w = f2bf(v.w);
    l16[l * D4 + tid] = h;
  }
}

// relation_weight f32[53][2304] -> bf16 padded [64][2304] (rows >=53 zero)
__global__ __launch_bounds__(256) void rwcvt(const float* __restrict__ rw,
                                             unsigned short* __restrict__ rw16) {
  const int idx = blockIdx.x * 256 + threadIdx.x;
  if (idx < CPAD * KTOT) {
    const int row = idx / KTOT;
    const float v = (row < FLATC) ? rw[idx] : 0.f;
    rw16[idx] = f2bf(v);
  }
}

// probs = lt @ rw^T + bias via bf16 MFMA. Block = 64 bags x 64 classes,
// 4 waves (wave = 16-bag subtile), 4 class-tiles per wave, K-loop of 72.
__global__ __launch_bounds__(256) void probs_mfma(
    const unsigned short* __restrict__ lt16,
    const unsigned short* __restrict__ rw16,
    const float* __restrict__ bias, float* __restrict__ outp) {
  const int wv = threadIdx.x >> 6;   // 0..3
  const int lane = threadIdx.x & 63;
  const int r = lane & 15;           // A-row / B-col within tile
  const int kg = lane >> 4;          // 0..3 k-group
  const int bagbase = blockIdx.x * 64 + wv * 16;

  f32x4 acc[4];
#pragma unroll
  for (int ct = 0; ct < 4; ct++) acc[ct] = (f32x4){0.f, 0.f, 0.f, 0.f};

  const unsigned short* ap = lt16 + (size_t)(bagbase + r) * KTOT + kg * 8;
  const unsigned short* bp[4];
#pragma unroll
  for (int ct = 0; ct < 4; ct++)
    bp[ct] = rw16 + (size_t)(ct * 16 + r) * KTOT + kg * 8;

  for (int k = 0; k < KTOT; k += 32) {
    const bf16x8 a = *(const bf16x8*)(ap + k);
#pragma unroll
    for (int ct = 0; ct < 4; ct++) {
      const bf16x8 bb = *(const bf16x8*)(bp[ct] + k);
      acc[ct] = __builtin_amdgcn_mfma_f32_16x16x32_bf16(a, bb, acc[ct], 0, 0, 0);
    }
  }

  // D mapping (m89-verified): col = lane&15, row = (lane>>4)*4 + reg
#pragma unroll
  for (int ct = 0; ct < 4; ct++) {
    const int col = ct * 16 + r;
    if (col < FLATC) {
      const float bv = bias[col];
#pragma unroll
      for (int reg = 0; reg < 4; reg++) {
        const int bag = bagbase + kg * 4 + reg;
        outp[(size_t)bag * FLATC + col] = acc[ct][reg] + bv;
      }
    }
  }
}

extern "C" void kernel_launch(void* const* d_in, const int* in_sizes, int n_in,
                              void* d_out, int out_size, void* d_ws,
                              size_t ws_size, hipStream_t stream) {
  const float* x = (const float*)d_in[0];
  const int* aq = (const int*)d_in[1];
  const int* scope = (const int*)d_in[2];
  const float* aw = (const float*)d_in[3];
  const float* rw = (const float*)d_in[4];
  const float* bias = (const float*)d_in[5];
  float* out = (float*)d_out;

  unsigned short* lt16 = (unsigned short*)d_ws;                  // 4096*2304*2 B
  unsigned short* rw16 = lt16 + (size_t)NBAGS * KTOT;            // 64*2304*2 B

  hipLaunchKernelGGL(bag_kernel, dim3(NBAGS), dim3(192), 0, stream, x, aq,
                     scope, aw, out, lt16);
  hipLaunchKernelGGL(rwcvt, dim3((CPAD * KTOT + 255) / 256), dim3(256), 0,
                     stream, rw, rw16);

  float* probs = out + (size_t)3 * NBAGS * DIM + (size_t)NBAGS * KTOT;
  hipLaunchKernelGGL(probs_mfma, dim3(NBAGS / 64), dim3(256), 0, stream, lt16,
                     rw16, bias, probs);
}

// Round 4
// 162.048 us; speedup vs baseline: 2.2656x; 1.1560x over previous
//
#include <hip/hip_runtime.h>
#include <math.h>

#define NSENT 65536
#define NBAGS 4096
#define DIM 768
#define D4 192            // DIM/4
#define FLATC 53
#define CPAD 64           // padded class count for MFMA
#define KTOT 2304         // 3*DIM
#define K4 576            // KTOT/4
#define CHUNK 512

typedef short bf16x8 __attribute__((ext_vector_type(8)));
typedef float f32x4 __attribute__((ext_vector_type(4)));

__device__ __forceinline__ float wsum(float v) {
#pragma unroll
  for (int o = 32; o; o >>= 1) v += __shfl_xor(v, o);
  return v;
}
__device__ __forceinline__ float wmax(float v) {
#pragma unroll
  for (int o = 32; o; o >>= 1) v = fmaxf(v, __shfl_xor(v, o));
  return v;
}
__device__ __forceinline__ float dot4(float4 a, float4 b) {
  return a.x * b.x + a.y * b.y + a.z * b.z + a.w * b.w;
}
// f32 -> bf16 round-to-nearest-even
__device__ __forceinline__ unsigned short f2bf(float f) {
  unsigned int u = __float_as_uint(f);
  return (unsigned short)((u + 0x7FFFu + ((u >> 16) & 1u)) >> 16);
}

// ---------------- Kernel L: logits for ALL sentences, wave = 2 sentences ----
// Grid-wide parallelism (32768 waves), no inter-phase barriers, no bag
// structure. Streams x exactly once; aw is L2-resident.
__global__ __launch_bounds__(256) void logit_kernel(
    const float* __restrict__ x, const int* __restrict__ q,
    const float* __restrict__ aw, float* __restrict__ lgout) {
  const int wid = (blockIdx.x * 256 + threadIdx.x) >> 6;
  const int lane = threadIdx.x & 63;
  const int n0 = wid * 2;
  if (n0 >= NSENT) return;
  const int n1 = n0 + 1;

  const int qa0 = q[3 * n0 + 0], qa1 = q[3 * n0 + 1], qa2 = q[3 * n0 + 2];
  const int qb0 = q[3 * n1 + 0], qb1 = q[3 * n1 + 1], qb2 = q[3 * n1 + 2];

  const float4* __restrict__ X4 = (const float4*)x;
  const float4* __restrict__ AW4 = (const float4*)aw;
  const float4* xr0 = X4 + (size_t)n0 * D4;
  const float4* xr1 = X4 + (size_t)n1 * D4;
  const float4* A00 = AW4 + (size_t)qa0 * D4;
  const float4* A01 = AW4 + (size_t)qa1 * D4;
  const float4* A02 = AW4 + (size_t)qa2 * D4;
  const float4* A10 = AW4 + (size_t)qb0 * D4;
  const float4* A11 = AW4 + (size_t)qb1 * D4;
  const float4* A12 = AW4 + (size_t)qb2 * D4;

  float p00 = 0.f, p01 = 0.f, p02 = 0.f;
  float p10 = 0.f, p11 = 0.f, p12 = 0.f;
#pragma unroll
  for (int j = 0; j < 3; j++) {
    const int idx = lane + 64 * j;
    const float4 x0 = xr0[idx];
    const float4 x1 = xr1[idx];
    p00 += dot4(x0, A00[idx]);
    p01 += dot4(x0, A01[idx]);
    p02 += dot4(x0, A02[idx]);
    p10 += dot4(x1, A10[idx]);
    p11 += dot4(x1, A11[idx]);
    p12 += dot4(x1, A12[idx]);
  }
  p00 = wsum(p00); p01 = wsum(p01); p02 = wsum(p02);
  p10 = wsum(p10); p11 = wsum(p11); p12 = wsum(p12);
  if (lane == 0) {
    lgout[3 * n0 + 0] = p00;
    lgout[3 * n0 + 1] = p01;
    lgout[3 * n0 + 2] = p02;
    lgout[3 * n1 + 0] = p10;
    lgout[3 * n1 + 1] = p11;
    lgout[3 * n1 + 2] = p12;
  }
}

// ---------------- Kernel W: per-bag softmax + weighted sum --------------
// Block per bag, 192 threads = 3 waves. Reads precomputed logits; x rows
// come from L2/L3 (just streamed by kernel L). Small LDS -> high occupancy.
__global__ __launch_bounds__(192) void bag_sum(
    const float* __restrict__ x, const float* __restrict__ lgin,
    const int* __restrict__ scope, float* __restrict__ out,
    unsigned short* __restrict__ lt16) {
  const int b = blockIdx.x;
  const int s0 = scope[b];
  const int s1 = scope[b + 1];
  const int len = s1 - s0;
  const int tid = threadIdx.x;
  const int wave = tid >> 6;
  const int lane = tid & 63;

  __shared__ float lg[CHUNK][3];
  __shared__ float sm[3], se[3];

  float m[3] = {-INFINITY, -INFINITY, -INFINITY};
  float dsum[3] = {0.f, 0.f, 0.f};
  float4 acc[3];
#pragma unroll
  for (int l = 0; l < 3; l++) acc[l] = make_float4(0.f, 0.f, 0.f, 0.f);

  const float4* __restrict__ X4 = (const float4*)x;

  for (int cs = 0; cs < len; cs += CHUNK) {
    const int clen = min(CHUNK, len - cs);

    // stage logits chunk (coalesced; layout matches lg[][3])
    for (int idx = tid; idx < 3 * clen; idx += 192)
      ((float*)lg)[idx] = lgin[(size_t)(s0 + cs) * 3 + idx];
    __syncthreads();

    // per-layer chunk max / exp / sum (wave w handles layer w)
    {
      const int l = wave;
      float cm = -INFINITY;
      for (int i = lane; i < clen; i += 64) cm = fmaxf(cm, lg[i][l]);
      cm = wmax(cm);
      const float mn = fmaxf(m[l], cm);
      float es = 0.f;
      for (int i = lane; i < clen; i += 64) {
        const float e = __expf(lg[i][l] - mn);
        es += e;
        lg[i][l] = e;  // unnormalized weight
      }
      es = wsum(es);
      if (lane == 0) {
        sm[l] = mn;
        se[l] = es;
      }
    }
    __syncthreads();

#pragma unroll
    for (int l = 0; l < 3; l++) {
      const float mn = sm[l];
      const float sc = __expf(m[l] - mn);  // exp(-inf)=0 first chunk
      m[l] = mn;
      dsum[l] = dsum[l] * sc + se[l];
      acc[l].x *= sc; acc[l].y *= sc; acc[l].z *= sc; acc[l].w *= sc;
    }

    // weighted accumulation, 4-sentence unroll; thread owns one float4 col
    {
      int i = 0;
      for (; i + 4 <= clen; i += 4) {
        float4 xv[4];
        float w0[4], w1[4], w2[4];
#pragma unroll
        for (int j = 0; j < 4; j++) {
          xv[j] = X4[(size_t)(s0 + cs + i + j) * D4 + tid];
          w0[j] = lg[i + j][0];
          w1[j] = lg[i + j][1];
          w2[j] = lg[i + j][2];
        }
#pragma unroll
        for (int j = 0; j < 4; j++) {
          acc[0].x += w0[j] * xv[j].x; acc[0].y += w0[j] * xv[j].y;
          acc[0].z += w0[j] * xv[j].z; acc[0].w += w0[j] * xv[j].w;
          acc[1].x += w1[j] * xv[j].x; acc[1].y += w1[j] * xv[j].y;
          acc[1].z += w1[j] * xv[j].z; acc[1].w += w1[j] * xv[j].w;
          acc[2].x += w2[j] * xv[j].x; acc[2].y += w2[j] * xv[j].y;
          acc[2].z += w2[j] * xv[j].z; acc[2].w += w2[j] * xv[j].w;
        }
      }
      for (; i < clen; i++) {
        const float a0 = lg[i][0], a1 = lg[i][1], a2 = lg[i][2];
        const float4 xv = X4[(size_t)(s0 + cs + i) * D4 + tid];
        acc[0].x += a0 * xv.x; acc[0].y += a0 * xv.y; acc[0].z += a0 * xv.z; acc[0].w += a0 * xv.w;
        acc[1].x += a1 * xv.x; acc[1].y += a1 * xv.y; acc[1].z += a1 * xv.z; acc[1].w += a1 * xv.w;
        acc[2].x += a2 * xv.x; acc[2].y += a2 * xv.y; acc[2].z += a2 * xv.z; acc[2].w += a2 * xv.w;
      }
    }
    __syncthreads();
  }

  // finalize: normalize, write both f32 layouts + bf16 copy for probs GEMM
  float4* o0 = (float4*)out;                              // stack [3][B][D]
  float4* o1 = (float4*)(out + (size_t)3 * NBAGS * DIM);  // lt [B][3*D]
  ushort4* l16 = (ushort4*)(lt16 + (size_t)b * KTOT);
#pragma unroll
  for (int l = 0; l < 3; l++) {
    const float inv = (dsum[l] > 0.f) ? (1.f / dsum[l]) : 0.f;
    float4 v = acc[l];
    v.x *= inv; v.y *= inv; v.z *= inv; v.w *= inv;
    o0[((size_t)l * NBAGS + b) * D4 + tid] = v;
    o1[(size_t)b * K4 + l * D4 + tid] = v;
    ushort4 h;
    h.x = f2bf(v.x); h.y = f2bf(v.y); h.z = f2bf(v.z); h.w = f2bf(v.w);
    l16[l * D4 + tid] = h;
  }
}

// relation_weight f32[53][2304] -> bf16 padded [64][2304] (rows >=53 zero)
__global__ __launch_bounds__(256) void rwcvt(const float* __restrict__ rw,
                                             unsigned short* __restrict__ rw16) {
  const int idx = blockIdx.x * 256 + threadIdx.x;
  if (idx < CPAD * KTOT) {
    const int row = idx / KTOT;
    const float v = (row < FLATC) ? rw[idx] : 0.f;
    rw16[idx] = f2bf(v);
  }
}

// probs = lt @ rw^T + bias via bf16 MFMA. Block = 64 bags x 64 classes.
__global__ __launch_bounds__(256) void probs_mfma(
    const unsigned short* __restrict__ lt16,
    const unsigned short* __restrict__ rw16,
    const float* __restrict__ bias, float* __restrict__ outp) {
  const int wv = threadIdx.x >> 6;
  const int lane = threadIdx.x & 63;
  const int r = lane & 15;
  const int kg = lane >> 4;
  const int bagbase = blockIdx.x * 64 + wv * 16;

  f32x4 acc[4];
#pragma unroll
  for (int ct = 0; ct < 4; ct++) acc[ct] = (f32x4){0.f, 0.f, 0.f, 0.f};

  const unsigned short* ap = lt16 + (size_t)(bagbase + r) * KTOT + kg * 8;
  const unsigned short* bp[4];
#pragma unroll
  for (int ct = 0; ct < 4; ct++)
    bp[ct] = rw16 + (size_t)(ct * 16 + r) * KTOT + kg * 8;

  for (int k = 0; k < KTOT; k += 32) {
    const bf16x8 a = *(const bf16x8*)(ap + k);
#pragma unroll
    for (int ct = 0; ct < 4; ct++) {
      const bf16x8 bb = *(const bf16x8*)(bp[ct] + k);
      acc[ct] = __builtin_amdgcn_mfma_f32_16x16x32_bf16(a, bb, acc[ct], 0, 0, 0);
    }
  }

  // D mapping (m89-verified): col = lane&15, row = (lane>>4)*4 + reg
#pragma unroll
  for (int ct = 0; ct < 4; ct++) {
    const int col = ct * 16 + r;
    if (col < FLATC) {
      const float bv = bias[col];
#pragma unroll
      for (int reg = 0; reg < 4; reg++) {
        const int bag = bagbase + kg * 4 + reg;
        outp[(size_t)bag * FLATC + col] = acc[ct][reg] + bv;
      }
    }
  }
}

extern "C" void kernel_launch(void* const* d_in, const int* in_sizes, int n_in,
                              void* d_out, int out_size, void* d_ws,
                              size_t ws_size, hipStream_t stream) {
  const float* x = (const float*)d_in[0];
  const int* aq = (const int*)d_in[1];
  const int* scope = (const int*)d_in[2];
  const float* aw = (const float*)d_in[3];
  const float* rw = (const float*)d_in[4];
  const float* bias = (const float*)d_in[5];
  float* out = (float*)d_out;

  unsigned short* lt16 = (unsigned short*)d_ws;        // 4096*2304 bf16
  unsigned short* rw16 = lt16 + (size_t)NBAGS * KTOT;  // 64*2304 bf16
  float* lgbuf = (float*)(rw16 + (size_t)CPAD * KTOT); // 65536*3 f32

  hipLaunchKernelGGL(logit_kernel, dim3(NSENT / 2 / 4), dim3(256), 0, stream,
                     x, aq, aw, lgbuf);
  hipLaunchKernelGGL(bag_sum, dim3(NBAGS), dim3(192), 0, stream, x, lgbuf,
                     scope, out, lt16);
  hipLaunchKernelGGL(rwcvt, dim3((CPAD * KTOT + 255) / 256), dim3(256), 0,
                     stream, rw, rw16);

  float* probs = out + (size_t)3 * NBAGS * DIM + (size_t)NBAGS * KTOT;
  hipLaunchKernelGGL(probs_mfma, dim3(NBAGS / 64), dim3(256), 0, stream, lt16,
                     rw16, bias, probs);
}